// Round 2
// baseline (14827.203 us; speedup 1.0000x reference)
//
#include <hip/hip_runtime.h>
#include <hip/hip_bf16.h>
#include <cstddef>
#include <type_traits>

typedef unsigned int u32;
typedef short bf16x8 __attribute__((ext_vector_type(8)));
typedef float f32x4 __attribute__((ext_vector_type(4)));
typedef _Float16 hf2 __attribute__((ext_vector_type(2)));

#define TC 256          // time-chunk length
#define NCHUNK 8        // 2048 / TC

// ---------- helpers ----------
__device__ __forceinline__ float sigf(float x) {
    return __builtin_amdgcn_rcpf(1.f + __expf(-x));
}
__device__ __forceinline__ float tanhf_fast(float x) {
    return 1.f - 2.f * __builtin_amdgcn_rcpf(1.f + __expf(2.f * x));
}
// fp16-pair dot with f32 accumulate: v_dot2_f32_f16 when available
__device__ __forceinline__ float dotp(u32 w, u32 h, float acc) {
#if __has_builtin(__builtin_amdgcn_fdot2)
    return __builtin_amdgcn_fdot2(__builtin_bit_cast(hf2, w),
                                  __builtin_bit_cast(hf2, h), acc, false);
#else
    hf2 wv = __builtin_bit_cast(hf2, w);
    hf2 hv = __builtin_bit_cast(hf2, h);
    return fmaf((float)wv.y, (float)hv.y, fmaf((float)wv.x, (float)hv.x, acc));
#endif
}
__device__ __forceinline__ float dot4(uint4 w, uint4 h, float acc) {
    acc = dotp(w.x, h.x, acc);
    acc = dotp(w.y, h.y, acc);
    acc = dotp(w.z, h.z, acc);
    acc = dotp(w.w, h.w, acc);
    return acc;
}

// ---------- dtype sniff: is this buffer bf16 (1) or fp32 (0)? ----------
__global__ void sniff(const u32* __restrict__ src, int nwords, int* __restrict__ flag) {
    __shared__ int cnt[256];
    int tid = threadIdx.x;
    size_t idx = (size_t)tid * (size_t)nwords / 256;
    u32 u = src[idx];
    int e = (u >> 7) & 0xFF;
    cnt[tid] = (e >= 100 && e <= 140) ? 1 : 0;
    __syncthreads();
    for (int s = 128; s > 0; s >>= 1) {
        if (tid < s) cnt[tid] += cnt[tid + s];
        __syncthreads();
    }
    if (tid == 0) *flag = (cnt[0] >= 144) ? 1 : 0;
}

// ---------- generic convert (bf16-or-f32 source) -> bf16 ----------
__global__ void conv_any(const void* __restrict__ src, __hip_bfloat16* __restrict__ dst,
                         int n, const int* __restrict__ flag) {
    int i = blockIdx.x * 256 + threadIdx.x;
    if (i >= n) return;
    if (*flag)
        dst[i] = ((const __hip_bfloat16*)src)[i];
    else
        dst[i] = __float2bfloat16(((const float*)src)[i]);
}

// ---------- per-chunk X convert: X[b][tc*256+ti][128] -> Xc_b[b][ti][128] ----------
__global__ void conv_x(const void* __restrict__ X, __hip_bfloat16* __restrict__ dst,
                       int tc, const int* __restrict__ flag) {
    int i = blockIdx.x * 256 + threadIdx.x;     // 2097152 total
    int b = i >> 15, rem = i & 32767, ti = rem >> 7, d = rem & 127;
    size_t s = ((size_t)(b * 2048 + tc * TC + ti) << 7) | d;
    float v = (*flag) ? __bfloat162float(((const __hip_bfloat16*)X)[s])
                      : ((const float*)X)[s];
    dst[i] = __float2bfloat16(v);
}

// ---------- pack Wh [256][1024] -> quad-major fp16-pair uint4 [32][1024] ----------
__global__ void pack_whq(const void* __restrict__ Wh, uint4* __restrict__ Whq,
                         const int* __restrict__ flag) {
    int i = blockIdx.x * 256 + threadIdx.x;   // 32768 total
    int q = i >> 10, n = i & 1023;
    float w[8];
    if (*flag) {
        const __hip_bfloat16* p = (const __hip_bfloat16*)Wh;
#pragma unroll
        for (int j = 0; j < 8; ++j) w[j] = __bfloat162float(p[(8 * q + j) * 1024 + n]);
    } else {
        const float* p = (const float*)Wh;
#pragma unroll
        for (int j = 0; j < 8; ++j) w[j] = p[(8 * q + j) * 1024 + n];
    }
    u32 r[4];
#pragma unroll
    for (int pp = 0; pp < 4; ++pp) {
        hf2 hp; hp.x = (_Float16)w[2 * pp]; hp.y = (_Float16)w[2 * pp + 1];
        r[pp] = __builtin_bit_cast(u32, hp);
    }
    Whq[i] = make_uint4(r[0], r[1], r[2], r[3]);
}

// ---------- GEMM: C[row(m)][N] = A[m][K](bf16) @ B[K][N](bf16) + bias ----------
template <typename OutT>
__global__ void gemm_bias(const __hip_bfloat16* __restrict__ A,
                          const __hip_bfloat16* __restrict__ B,
                          const __hip_bfloat16* __restrict__ bias,
                          OutT* __restrict__ C, int N, int K,
                          long strideA, long strideC) {
    __shared__ short As[64 * 72];
    __shared__ short Bs[64 * 72];
    const int tid = threadIdx.x;
    const int n0 = blockIdx.x * 64;
    const int m0 = blockIdx.y * 64;
    const int w = tid >> 6, lane = tid & 63;
    const int lm = lane & 15, lq = lane >> 4;

    f32x4 acc[4];
#pragma unroll
    for (int i = 0; i < 4; ++i) acc[i] = (f32x4){0.f, 0.f, 0.f, 0.f};

    const int kchunks = K >> 6;
    for (int kc = 0; kc < kchunks; ++kc) {
#pragma unroll
        for (int p = 0; p < 2; ++p) {
            int m = m0 + (tid >> 3) + 32 * p;
            int ch = tid & 7;
            size_t aoff = ((size_t)(m >> 8) * strideA + (m & 255)) * K;
            uint4 v = *(const uint4*)(A + aoff + kc * 64 + ch * 8);
            *(uint4*)(As + ((tid >> 3) + 32 * p) * 72 + ch * 8) = v;
        }
#pragma unroll
        for (int p = 0; p < 2; ++p) {
            int k  = (tid >> 3) + 32 * p;
            int ne = (tid & 7) * 8;
            uint4 v = *(const uint4*)(B + (size_t)(kc * 64 + k) * N + n0 + ne);
            const short* sv = (const short*)&v;
#pragma unroll
            for (int e = 0; e < 8; ++e) Bs[(ne + e) * 72 + k] = sv[e];
        }
        __syncthreads();
#pragma unroll
        for (int ks = 0; ks < 2; ++ks) {
            bf16x8 af = *(const bf16x8*)(As + (16 * w + lm) * 72 + ks * 32 + lq * 8);
#pragma unroll
            for (int nt = 0; nt < 4; ++nt) {
                bf16x8 bfr = *(const bf16x8*)(Bs + (nt * 16 + lm) * 72 + ks * 32 + lq * 8);
                acc[nt] = __builtin_amdgcn_mfma_f32_16x16x32_bf16(af, bfr, acc[nt], 0, 0, 0);
            }
        }
        __syncthreads();
    }
#pragma unroll
    for (int nt = 0; nt < 4; ++nt) {
        int col = n0 + nt * 16 + lm;
        float bv = __bfloat162float(bias[col]);
#pragma unroll
        for (int r = 0; r < 4; ++r) {
            int mrow = m0 + 16 * w + lq * 4 + r;
            size_t coff = ((size_t)(mrow >> 8) * strideC + (mrow & 255)) * N;
            float v = acc[nt][r] + bv;
            if constexpr (std::is_same_v<OutT, _Float16>)
                C[coff + col] = (_Float16)v;
            else if constexpr (std::is_same_v<OutT, float>)
                C[coff + col] = v;
            else
                C[coff + col] = __float2bfloat16(v);
        }
    }
}

// ---------- LSTM recurrence chunk: one WG (512 threads) per batch ----------
// Each thread owns 2 gate columns: tid and tid+512.
// Weight quads (8 k-values each), 32 total per column:
//   q in [0,LDSQ)            : LDS, all 1024 columns           (144 KB)
//   q in [LDSQ,LDSQ+REGQ)    : VGPR-resident, both columns     (42 uint4)
//   q in [LDSQ+REGQ,32)      : streamed from L2 (tiny)
#define LDSQ 9
#define REGQ 21
#define STRQ (32 - LDSQ - REGQ)   // 2

__global__ __launch_bounds__(512, 2) void lstm_rec_chunk(
        const _Float16* __restrict__ xg_c,    // [64][TC][1024]
        const uint4* __restrict__ Whq,        // [32][1024] fp16-pair quads
        __hip_bfloat16* __restrict__ hs_c,    // [64][TC][256]
        float* __restrict__ hstate,           // [64][256]
        float* __restrict__ cstate,           // [64][256]
        int first) {
    const int tid = threadIdx.x;   // 0..511
    const int b = blockIdx.x;
    __shared__ uint4 wlds[LDSQ * 1024];           // 144 KB
    __shared__ float garr[1024];                  // 4 KB
    __shared__ alignas(16) u32 hpair[128];        // h as fp16 pairs, 512 B

    // stage LDS weight quads 0..LDSQ-1 (linear copy, coalesced)
#pragma unroll
    for (int i = 0; i < LDSQ * 2; ++i)
        wlds[i * 512 + tid] = Whq[i * 512 + tid];

    uint4 wqa[REGQ], wqb[REGQ];
#pragma unroll
    for (int r = 0; r < REGQ; ++r) {
        wqa[r] = Whq[(LDSQ + r) * 1024 + tid];
        wqb[r] = Whq[(LDSQ + r) * 1024 + tid + 512];
    }
    const uint4* wsa = Whq + (LDSQ + REGQ) * 1024 + tid;
    const uint4* wsb = wsa + 512;

    float c = 0.f;
    if (tid < 256) {
        float h0 = first ? 0.f : hstate[b * 256 + tid];
        if (!first) c = cstate[b * 256 + tid];
        float hp = __shfl_xor(h0, 1);
        if (!(tid & 1)) {
            hf2 p; p.x = (_Float16)h0; p.y = (_Float16)hp;
            hpair[tid >> 1] = __builtin_bit_cast(u32, p);
        }
    }
    __syncthreads();

    const _Float16* xgpA = xg_c + (size_t)b * TC * 1024 + tid;
    const _Float16* xgpB = xgpA + 512;
    __hip_bfloat16* hsp = hs_c + (size_t)b * TC * 256 + tid;   // used by tid<256
    const uint4* hq4 = (const uint4*)hpair;

    float xa = (float)xgpA[0];
    float xb = (float)xgpB[0];

    for (int t = 0; t < TC; ++t) {
        // prefetch next step's xg (hides L2/HBM latency under the dot chain)
        float nxa = 0.f, nxb = 0.f;
        if (t + 1 < TC) {
            nxa = (float)xgpA[(size_t)(t + 1) * 1024];
            nxb = (float)xgpB[(size_t)(t + 1) * 1024];
        }
        float aA[4] = {xa, 0.f, 0.f, 0.f};
        float aB[4] = {xb, 0.f, 0.f, 0.f};
#pragma unroll
        for (int q = 0; q < 32; ++q) {
            uint4 hv = hq4[q];                       // uniform-address broadcast b128
            uint4 wa, wb;
            if (q < LDSQ) {
                wa = wlds[q * 1024 + tid];
                wb = wlds[q * 1024 + tid + 512];
            } else if (q < LDSQ + REGQ) {
                wa = wqa[q - LDSQ];
                wb = wqb[q - LDSQ];
            } else {
                wa = wsa[(size_t)(q - LDSQ - REGQ) * 1024];
                wb = wsb[(size_t)(q - LDSQ - REGQ) * 1024];
            }
            aA[q & 3] = dot4(wa, hv, aA[q & 3]);
            aB[q & 3] = dot4(wb, hv, aB[q & 3]);
        }
        float gA = (aA[0] + aA[1]) + (aA[2] + aA[3]);
        float gB = (aB[0] + aB[1]) + (aB[2] + aB[3]);

        // colA = tid      : forget (tid<256) / input (tid>=256)   -> sigmoid
        // colB = tid+512  : output (tid<256) / cell  (tid>=256)   -> sigmoid/tanh
        float s0 = sigf(gA);
        float s1 = (tid < 256) ? sigf(gB) : tanhf_fast(gB);
        garr[tid] = s0;
        garr[tid + 512] = s1;
        __syncthreads();
        if (tid < 256) {
            float f  = garr[tid];
            float ig = garr[tid + 256];
            float og = garr[tid + 512];
            float ct = garr[tid + 768];
            c = c * f + ct * ig;
            float h = og * tanhf_fast(c);
            hsp[(size_t)t * 256] = __float2bfloat16(h);
            float hp = __shfl_xor(h, 1);
            if (!(tid & 1)) {
                hf2 p; p.x = (_Float16)h; p.y = (_Float16)hp;
                hpair[tid >> 1] = __builtin_bit_cast(u32, p);
            }
        }
        __syncthreads();
        xa = nxa; xb = nxb;
    }
    if (tid < 256) {
        hf2 p = __builtin_bit_cast(hf2, hpair[tid >> 1]);
        hstate[b * 256 + tid] = (float)((tid & 1) ? p.y : p.x);
        cstate[b * 256 + tid] = c;
    }
}

// ---------- launch ----------
extern "C" void kernel_launch(void* const* d_in, const int* in_sizes, int n_in,
                              void* d_out, int out_size, void* d_ws, size_t ws_size,
                              hipStream_t stream) {
    const void* X    = d_in[0];  // [64,2048,128] fp32 (sniffed)
    const void* Wx   = d_in[1];  // [128,1024]
    const void* Wh   = d_in[2];  // [256,1024]
    const void* bg   = d_in[3];  // [1024]
    const void* Wout = d_in[4];  // [256,128]
    const void* bout = d_in[5];  // [128]
    float* out = (float*)d_out;  // [64,2048,128] fp32 (reference output dtype)

    // workspace layout (~47.2 MB)
    char* ws = (char*)d_ws;
    _Float16* xg_c        = (_Float16*)(ws + 0);                 // 33554432
    __hip_bfloat16* Xc_b  = (__hip_bfloat16*)(ws + 33554432);    //  4194304
    __hip_bfloat16* hs_c  = (__hip_bfloat16*)(ws + 37748736);    //  8388608
    uint4* Whq            = (uint4*)(ws + 46137344);             //   524288
    __hip_bfloat16* Wxb   = (__hip_bfloat16*)(ws + 46661632);    //   262144
    __hip_bfloat16* Woutb = (__hip_bfloat16*)(ws + 46923776);    //    65536
    __hip_bfloat16* bgb   = (__hip_bfloat16*)(ws + 46989312);    //     2048
    __hip_bfloat16* boutb = (__hip_bfloat16*)(ws + 46991360);    //      512
    float* hstate         = (float*)(ws + 46991872);             //    65536
    float* cstate         = (float*)(ws + 47057408);             //    65536
    int* flags            = (int*)(ws + 47122944);               //       64

    // 1) per-tensor dtype sniff
    for (int i = 0; i < 6; ++i)
        sniff<<<dim3(1), dim3(256), 0, stream>>>((const u32*)d_in[i],
                                                 in_sizes[i] / 2, flags + i);
    // 2) canonicalize weights/biases to bf16 (and Wh to quad-major fp16 pairs)
    conv_any<<<dim3(512), dim3(256), 0, stream>>>(Wx, Wxb, 131072, flags + 1);
    conv_any<<<dim3(128), dim3(256), 0, stream>>>(Wout, Woutb, 32768, flags + 4);
    conv_any<<<dim3(4),   dim3(256), 0, stream>>>(bg, bgb, 1024, flags + 3);
    conv_any<<<dim3(1),   dim3(256), 0, stream>>>(bout, boutb, 128, flags + 5);
    pack_whq<<<dim3(128), dim3(256), 0, stream>>>(Wh, Whq, flags + 2);

    for (int tc = 0; tc < NCHUNK; ++tc) {
        // 3) X chunk -> bf16 [64][256][128]
        conv_x<<<dim3(8192), dim3(256), 0, stream>>>(X, Xc_b, tc, flags + 0);
        // 4) xg_c = Xc_b @ Wxb + bgb : M=16384, N=1024, K=128
        gemm_bias<_Float16><<<dim3(16, 256), dim3(256), 0, stream>>>(
            Xc_b, Wxb, bgb, xg_c, 1024, 128, 256L, 256L);
        // 5) recurrence over TC steps
        lstm_rec_chunk<<<dim3(64), dim3(512), 0, stream>>>(
            xg_c, Whq, hs_c, hstate, cstate, tc == 0 ? 1 : 0);
        // 6) outc = hs_c @ Woutb + boutb : M=16384, N=128, K=256  (fp32 out)
        float* outc = out + (size_t)tc * TC * 128;
        gemm_bias<float><<<dim3(2, 256), dim3(256), 0, stream>>>(
            hs_c, Woutb, boutb, outc, 128, 256, 256L, 2048L);
    }
}

// Round 3
// 8398.344 us; speedup vs baseline: 1.7655x; 1.7655x over previous
//
#include <hip/hip_runtime.h>
#include <hip/hip_bf16.h>
#include <cstddef>
#include <type_traits>

typedef unsigned int u32;
typedef short bf16x8 __attribute__((ext_vector_type(8)));
typedef float f32x4 __attribute__((ext_vector_type(4)));
typedef _Float16 hf2 __attribute__((ext_vector_type(2)));

#define TC 256          // time-chunk length
#define NCHUNK 8        // 2048 / TC

// ---------- helpers ----------
__device__ __forceinline__ float sigf(float x) {
    return __builtin_amdgcn_rcpf(1.f + __expf(-x));
}
__device__ __forceinline__ float tanhf_fast(float x) {
    return 1.f - 2.f * __builtin_amdgcn_rcpf(1.f + __expf(2.f * x));
}
// fp16-pair dot with f32 accumulate: v_dot2_f32_f16 when available
__device__ __forceinline__ float dotp(u32 w, u32 h, float acc) {
#if __has_builtin(__builtin_amdgcn_fdot2)
    return __builtin_amdgcn_fdot2(__builtin_bit_cast(hf2, w),
                                  __builtin_bit_cast(hf2, h), acc, false);
#else
    hf2 wv = __builtin_bit_cast(hf2, w);
    hf2 hv = __builtin_bit_cast(hf2, h);
    return fmaf((float)wv.y, (float)hv.y, fmaf((float)wv.x, (float)hv.x, acc));
#endif
}
__device__ __forceinline__ float dot4(uint4 w, uint4 h, float acc) {
    acc = dotp(w.x, h.x, acc);
    acc = dotp(w.y, h.y, acc);
    acc = dotp(w.z, h.z, acc);
    acc = dotp(w.w, h.w, acc);
    return acc;
}

// ---------- dtype sniff: is this buffer bf16 (1) or fp32 (0)? ----------
__global__ void sniff(const u32* __restrict__ src, int nwords, int* __restrict__ flag) {
    __shared__ int cnt[256];
    int tid = threadIdx.x;
    size_t idx = (size_t)tid * (size_t)nwords / 256;
    u32 u = src[idx];
    int e = (u >> 7) & 0xFF;
    cnt[tid] = (e >= 100 && e <= 140) ? 1 : 0;
    __syncthreads();
    for (int s = 128; s > 0; s >>= 1) {
        if (tid < s) cnt[tid] += cnt[tid + s];
        __syncthreads();
    }
    if (tid == 0) *flag = (cnt[0] >= 144) ? 1 : 0;
}

// ---------- generic convert (bf16-or-f32 source) -> bf16 ----------
__global__ void conv_any(const void* __restrict__ src, __hip_bfloat16* __restrict__ dst,
                         int n, const int* __restrict__ flag) {
    int i = blockIdx.x * 256 + threadIdx.x;
    if (i >= n) return;
    if (*flag)
        dst[i] = ((const __hip_bfloat16*)src)[i];
    else
        dst[i] = __float2bfloat16(((const float*)src)[i]);
}

// ---------- per-chunk X convert: X[b][tc*256+ti][128] -> Xc_b[b][ti][128] ----------
__global__ void conv_x(const void* __restrict__ X, __hip_bfloat16* __restrict__ dst,
                       int tc, const int* __restrict__ flag) {
    int i = blockIdx.x * 256 + threadIdx.x;     // 2097152 total
    int b = i >> 15, rem = i & 32767, ti = rem >> 7, d = rem & 127;
    size_t s = ((size_t)(b * 2048 + tc * TC + ti) << 7) | d;
    float v = (*flag) ? __bfloat162float(((const __hip_bfloat16*)X)[s])
                      : ((const float*)X)[s];
    dst[i] = __float2bfloat16(v);
}

// ---------- pack Wh [256][1024] -> quad-major fp16-pair uint4 [32][1024] ----------
__global__ void pack_whq(const void* __restrict__ Wh, uint4* __restrict__ Whq,
                         const int* __restrict__ flag) {
    int i = blockIdx.x * 256 + threadIdx.x;   // 32768 total
    int q = i >> 10, n = i & 1023;
    float w[8];
    if (*flag) {
        const __hip_bfloat16* p = (const __hip_bfloat16*)Wh;
#pragma unroll
        for (int j = 0; j < 8; ++j) w[j] = __bfloat162float(p[(8 * q + j) * 1024 + n]);
    } else {
        const float* p = (const float*)Wh;
#pragma unroll
        for (int j = 0; j < 8; ++j) w[j] = p[(8 * q + j) * 1024 + n];
    }
    u32 r[4];
#pragma unroll
    for (int pp = 0; pp < 4; ++pp) {
        hf2 hp; hp.x = (_Float16)w[2 * pp]; hp.y = (_Float16)w[2 * pp + 1];
        r[pp] = __builtin_bit_cast(u32, hp);
    }
    Whq[i] = make_uint4(r[0], r[1], r[2], r[3]);
}

// ---------- GEMM: C[row(m)][N] = A[m][K](bf16) @ B[K][N](bf16) + bias ----------
template <typename OutT>
__global__ void gemm_bias(const __hip_bfloat16* __restrict__ A,
                          const __hip_bfloat16* __restrict__ B,
                          const __hip_bfloat16* __restrict__ bias,
                          OutT* __restrict__ C, int N, int K,
                          long strideA, long strideC) {
    __shared__ short As[64 * 72];
    __shared__ short Bs[64 * 72];
    const int tid = threadIdx.x;
    const int n0 = blockIdx.x * 64;
    const int m0 = blockIdx.y * 64;
    const int w = tid >> 6, lane = tid & 63;
    const int lm = lane & 15, lq = lane >> 4;

    f32x4 acc[4];
#pragma unroll
    for (int i = 0; i < 4; ++i) acc[i] = (f32x4){0.f, 0.f, 0.f, 0.f};

    const int kchunks = K >> 6;
    for (int kc = 0; kc < kchunks; ++kc) {
#pragma unroll
        for (int p = 0; p < 2; ++p) {
            int m = m0 + (tid >> 3) + 32 * p;
            int ch = tid & 7;
            size_t aoff = ((size_t)(m >> 8) * strideA + (m & 255)) * K;
            uint4 v = *(const uint4*)(A + aoff + kc * 64 + ch * 8);
            *(uint4*)(As + ((tid >> 3) + 32 * p) * 72 + ch * 8) = v;
        }
#pragma unroll
        for (int p = 0; p < 2; ++p) {
            int k  = (tid >> 3) + 32 * p;
            int ne = (tid & 7) * 8;
            uint4 v = *(const uint4*)(B + (size_t)(kc * 64 + k) * N + n0 + ne);
            const short* sv = (const short*)&v;
#pragma unroll
            for (int e = 0; e < 8; ++e) Bs[(ne + e) * 72 + k] = sv[e];
        }
        __syncthreads();
#pragma unroll
        for (int ks = 0; ks < 2; ++ks) {
            bf16x8 af = *(const bf16x8*)(As + (16 * w + lm) * 72 + ks * 32 + lq * 8);
#pragma unroll
            for (int nt = 0; nt < 4; ++nt) {
                bf16x8 bfr = *(const bf16x8*)(Bs + (nt * 16 + lm) * 72 + ks * 32 + lq * 8);
                acc[nt] = __builtin_amdgcn_mfma_f32_16x16x32_bf16(af, bfr, acc[nt], 0, 0, 0);
            }
        }
        __syncthreads();
    }
#pragma unroll
    for (int nt = 0; nt < 4; ++nt) {
        int col = n0 + nt * 16 + lm;
        float bv = __bfloat162float(bias[col]);
#pragma unroll
        for (int r = 0; r < 4; ++r) {
            int mrow = m0 + 16 * w + lq * 4 + r;
            size_t coff = ((size_t)(mrow >> 8) * strideC + (mrow & 255)) * N;
            float v = acc[nt][r] + bv;
            if constexpr (std::is_same_v<OutT, _Float16>)
                C[coff + col] = (_Float16)v;
            else if constexpr (std::is_same_v<OutT, float>)
                C[coff + col] = v;
            else
                C[coff + col] = __float2bfloat16(v);
        }
    }
}

// ---------- LSTM recurrence chunk: one WG (256 threads) per batch ----------
// Thread j owns ALL FOUR gate columns of h-column j:
//   forget=j, input=j+256, output=j+512, cell=j+768.
// -> gate exchange is thread-local; ONE barrier per step (hpair visibility).
// Weight quads (8 k-values each), 32 per column, ALL resident:
//   q in [0,LDSQ)   : LDS (144 KB)
//   q in [LDSQ,32)  : VGPRs (REGQ=23 quads x 4 cols = 92 uint4 = 368 VGPRs)
// No per-step global weight traffic at all.
#define LDSQ 9
#define REGQ 23

__global__ __launch_bounds__(256, 1) void lstm_rec_chunk(
        const _Float16* __restrict__ xg_c,    // [64][TC][1024]
        const uint4* __restrict__ Whq,        // [32][1024] fp16-pair quads
        __hip_bfloat16* __restrict__ hs_c,    // [64][TC][256]
        float* __restrict__ hstate,           // [64][256]
        float* __restrict__ cstate,           // [64][256]
        int first) {
    const int tid = threadIdx.x;   // 0..255
    const int b = blockIdx.x;
    __shared__ uint4 wlds[LDSQ * 1024];           // 144 KB
    __shared__ alignas(16) u32 hpair[128];        // h as fp16 pairs, 512 B

    // stage LDS weight quads 0..LDSQ-1 (coalesced)
#pragma unroll
    for (int i = 0; i < LDSQ * 4; ++i)
        wlds[i * 256 + tid] = Whq[i * 256 + tid];

    // register-resident weight quads, separate statically-indexed arrays per column
    uint4 wr0[REGQ], wr1[REGQ], wr2[REGQ], wr3[REGQ];
#pragma unroll
    for (int r = 0; r < REGQ; ++r) {
        wr0[r] = Whq[(LDSQ + r) * 1024 + tid];
        wr1[r] = Whq[(LDSQ + r) * 1024 + tid + 256];
        wr2[r] = Whq[(LDSQ + r) * 1024 + tid + 512];
        wr3[r] = Whq[(LDSQ + r) * 1024 + tid + 768];
    }

    float h = first ? 0.f : hstate[b * 256 + tid];
    float c = first ? 0.f : cstate[b * 256 + tid];
    {
        float hp = __shfl_xor(h, 1);
        if (!(tid & 1)) {
            hf2 p; p.x = (_Float16)h; p.y = (_Float16)hp;
            hpair[tid >> 1] = __builtin_bit_cast(u32, p);
        }
    }
    __syncthreads();

    const _Float16* xgp = xg_c + (size_t)b * TC * 1024 + tid;
    __hip_bfloat16* hsp = hs_c + (size_t)b * TC * 256 + tid;
    const uint4* hq4 = (const uint4*)hpair;

    for (int t = 0; t < TC; ++t) {
        // xg loads issued first; consumed only AFTER the dot chain (latency hidden)
        float x0 = (float)xgp[(size_t)t * 1024];
        float x1 = (float)xgp[(size_t)t * 1024 + 256];
        float x2 = (float)xgp[(size_t)t * 1024 + 512];
        float x3 = (float)xgp[(size_t)t * 1024 + 768];

        float a0[4] = {0.f, 0.f, 0.f, 0.f};
        float a1[4] = {0.f, 0.f, 0.f, 0.f};
        float a2[4] = {0.f, 0.f, 0.f, 0.f};
        float a3[4] = {0.f, 0.f, 0.f, 0.f};

        // LDS-resident quads
#pragma unroll
        for (int q = 0; q < LDSQ; ++q) {
            uint4 hv = hq4[q];                     // uniform-address broadcast b128
            uint4 w0 = wlds[q * 1024 + tid];
            uint4 w1 = wlds[q * 1024 + tid + 256];
            uint4 w2 = wlds[q * 1024 + tid + 512];
            uint4 w3 = wlds[q * 1024 + tid + 768];
            a0[q & 3] = dot4(w0, hv, a0[q & 3]);
            a1[q & 3] = dot4(w1, hv, a1[q & 3]);
            a2[q & 3] = dot4(w2, hv, a2[q & 3]);
            a3[q & 3] = dot4(w3, hv, a3[q & 3]);
        }
        // VGPR-resident quads (static indices only)
#pragma unroll
        for (int r = 0; r < REGQ; ++r) {
            uint4 hv = hq4[LDSQ + r];
            a0[(LDSQ + r) & 3] = dot4(wr0[r], hv, a0[(LDSQ + r) & 3]);
            a1[(LDSQ + r) & 3] = dot4(wr1[r], hv, a1[(LDSQ + r) & 3]);
            a2[(LDSQ + r) & 3] = dot4(wr2[r], hv, a2[(LDSQ + r) & 3]);
            a3[(LDSQ + r) & 3] = dot4(wr3[r], hv, a3[(LDSQ + r) & 3]);
        }

        float gf = x0 + (a0[0] + a0[1]) + (a0[2] + a0[3]);
        float gi = x1 + (a1[0] + a1[1]) + (a1[2] + a1[3]);
        float go = x2 + (a2[0] + a2[1]) + (a2[2] + a2[3]);
        float gc = x3 + (a3[0] + a3[1]) + (a3[2] + a3[3]);

        float f  = sigf(gf);
        float ig = sigf(gi);
        float og = sigf(go);
        float ct = tanhf_fast(gc);
        c = c * f + ct * ig;
        h = og * tanhf_fast(c);
        hsp[(size_t)t * 256] = __float2bfloat16(h);

        float hp = __shfl_xor(h, 1);
        if (!(tid & 1)) {
            hf2 p; p.x = (_Float16)h; p.y = (_Float16)hp;
            hpair[tid >> 1] = __builtin_bit_cast(u32, p);
        }
        __syncthreads();
    }
    hstate[b * 256 + tid] = h;
    cstate[b * 256 + tid] = c;
}

// ---------- launch ----------
extern "C" void kernel_launch(void* const* d_in, const int* in_sizes, int n_in,
                              void* d_out, int out_size, void* d_ws, size_t ws_size,
                              hipStream_t stream) {
    const void* X    = d_in[0];  // [64,2048,128] fp32 (sniffed)
    const void* Wx   = d_in[1];  // [128,1024]
    const void* Wh   = d_in[2];  // [256,1024]
    const void* bg   = d_in[3];  // [1024]
    const void* Wout = d_in[4];  // [256,128]
    const void* bout = d_in[5];  // [128]
    float* out = (float*)d_out;  // [64,2048,128] fp32 (reference output dtype)

    // workspace layout (~47.2 MB)
    char* ws = (char*)d_ws;
    _Float16* xg_c        = (_Float16*)(ws + 0);                 // 33554432
    __hip_bfloat16* Xc_b  = (__hip_bfloat16*)(ws + 33554432);    //  4194304
    __hip_bfloat16* hs_c  = (__hip_bfloat16*)(ws + 37748736);    //  8388608
    uint4* Whq            = (uint4*)(ws + 46137344);             //   524288
    __hip_bfloat16* Wxb   = (__hip_bfloat16*)(ws + 46661632);    //   262144
    __hip_bfloat16* Woutb = (__hip_bfloat16*)(ws + 46923776);    //    65536
    __hip_bfloat16* bgb   = (__hip_bfloat16*)(ws + 46989312);    //     2048
    __hip_bfloat16* boutb = (__hip_bfloat16*)(ws + 46991360);    //      512
    float* hstate         = (float*)(ws + 46991872);             //    65536
    float* cstate         = (float*)(ws + 47057408);             //    65536
    int* flags            = (int*)(ws + 47122944);               //       64

    // 1) per-tensor dtype sniff
    for (int i = 0; i < 6; ++i)
        sniff<<<dim3(1), dim3(256), 0, stream>>>((const u32*)d_in[i],
                                                 in_sizes[i] / 2, flags + i);
    // 2) canonicalize weights/biases to bf16 (and Wh to quad-major fp16 pairs)
    conv_any<<<dim3(512), dim3(256), 0, stream>>>(Wx, Wxb, 131072, flags + 1);
    conv_any<<<dim3(128), dim3(256), 0, stream>>>(Wout, Woutb, 32768, flags + 4);
    conv_any<<<dim3(4),   dim3(256), 0, stream>>>(bg, bgb, 1024, flags + 3);
    conv_any<<<dim3(1),   dim3(256), 0, stream>>>(bout, boutb, 128, flags + 5);
    pack_whq<<<dim3(128), dim3(256), 0, stream>>>(Wh, Whq, flags + 2);

    for (int tc = 0; tc < NCHUNK; ++tc) {
        // 3) X chunk -> bf16 [64][256][128]
        conv_x<<<dim3(8192), dim3(256), 0, stream>>>(X, Xc_b, tc, flags + 0);
        // 4) xg_c = Xc_b @ Wxb + bgb : M=16384, N=1024, K=128
        gemm_bias<_Float16><<<dim3(16, 256), dim3(256), 0, stream>>>(
            Xc_b, Wxb, bgb, xg_c, 1024, 128, 256L, 256L);
        // 5) recurrence over TC steps
        lstm_rec_chunk<<<dim3(64), dim3(256), 0, stream>>>(
            xg_c, Whq, hs_c, hstate, cstate, tc == 0 ? 1 : 0);
        // 6) outc = hs_c @ Woutb + boutb : M=16384, N=128, K=256  (fp32 out)
        float* outc = out + (size_t)tc * TC * 128;
        gemm_bias<float><<<dim3(2, 256), dim3(256), 0, stream>>>(
            hs_c, Woutb, boutb, outc, 128, 256, 256L, 2048L);
    }
}